// Round 6
// baseline (210.476 us; speedup 1.0000x reference)
//
#include <hip/hip_runtime.h>
#include <hip/hip_bf16.h>

// out[64,8192] = x[64,8192] @ dequant(w2bit)[8192,8192]^T + bias
#define B_    64
#define IN_   8192
#define OUT_  8192
#define NG_   128      // groups per row (IN/64)
#define PB_   2048     // packed bytes per weight row (IN/4)

#define KSPLIT 8
#define KC     1024    // k per block (two 512-k LDS phases, 2 superblocks each)
#define CGS    2       // col-groups (16 cols) per wave -> 32 cols/wave, 128/block

typedef float f32x4 __attribute__((ext_vector_type(4)));
typedef short s16x8 __attribute__((ext_vector_type(8)));
union FU { float f; unsigned u; };

// Poison-proof completion signature: hi and lo 32-bit halves always differ,
// so a uniform fill pattern (any repeated <=32-bit value) can never equal it.
__device__ __forceinline__ unsigned long long sig(int bid) {
    unsigned hi = 0xAB000000u | (unsigned)bid;
    return ((unsigned long long)hi << 32) | (hi ^ 0xFFFF00FFu);
}

// Grid = 64 col-blocks(128 cols) x 8 k-splits = 512 blocks = 2/CU, one round,
// all co-resident (so flag polling cannot deadlock). Block = 256 thr = 4
// waves x 32 cols. k-splits 0..6 write private partial planes in ws; the
// kidx==7 block of each col-group keeps its tile in LDS, waits for its 7
// siblings via device-scope signature flags, then reduces + bias -> out.
// (Replaces the separate k_reduce dispatch.)
//
// K permuted inside 256-k SUPERBLOCKS (same permutation on x and w, dot
// products unchanged): MFMA kstep b (0..7), lane q, elem j <-> k =
// S256 + q*64 + b*8 + j. A lane's weights for one superblock = 16 contiguous
// bytes; per block each weight row is read as 256 contiguous bytes (full HBM
// sectors). A lane's 64-k range = exactly one quant group: g = S256/64 + q.
__global__ __launch_bounds__(256, 2) void k_main(
    const float* __restrict__ x,
    const unsigned char* __restrict__ wp,
    const float* __restrict__ scales,
    const int* __restrict__ zps,
    const float* __restrict__ bias,
    float* __restrict__ out,
    float* __restrict__ part)
{
    __shared__ uint4 x_lds[4096];   // 64 KB: one 512-k phase, frag-slot order

    const int tid  = threadIdx.x;
    const int wave = tid >> 6;
    const int lane = tid & 63;
    const int q    = lane >> 4;
    const int nn   = lane & 15;

    const int bid     = blockIdx.x;
    const int kidx    = bid & (KSPLIT - 1);
    const int nblk    = bid >> 3;
    const int kbase   = kidx * KC;
    const int colbase = nblk * 128 + wave * 32;

    // ---- dtype-mode detection: wave-uniform scalar loads ----
    const unsigned d0 = ((const unsigned*)wp)[0];
    const unsigned d1 = ((const unsigned*)wp)[1];
    const bool u8mode = (d0 | d1) > 255u;
    const bool zgen   = (zps[0] != 2) || (zps[OUT_ * NG_ - 1] != 2);

    // ---- weight loads: speculative packed-u8 path issued FIRST (real runtime
    // format) for maximal MLP; in-bounds in both modes. 8 x 16 B per lane
    // covers both phases; each load is row-contiguous.
    uint4 w16[2][2][CGS];
    const int wb = (kbase >> 2) + q * 16;
#pragma unroll
    for (int ph = 0; ph < 2; ++ph)
#pragma unroll
        for (int sb = 0; sb < 2; ++sb)
#pragma unroll
            for (int cg = 0; cg < CGS; ++cg) {
                int n = colbase + cg * 16 + nn;
                w16[ph][sb][cg] =
                    *(const uint4*)(wp + n * PB_ + wb + ph * 128 + sb * 64);
            }

    // ---- stage one 512-k phase: load fp32, convert, ds_write_b128 ----
    // slot (sg = sb*32 + b*4 + mt, l = q'*16 + nn') holds
    // x[mt*16+nn'][kph + sb*256 + q'*64 + b*8 .. +8) as 8 bf16.
    // thread (wave,q,nn) iter i: val = i*32+q*8 -> sb=val>>8, q'=(val>>6)&3,
    // b=(val>>3)&7; row = wave*16+nn. 16 rows x 128 B per wave-iteration.
    auto stage = [&](int kph) {
#pragma unroll
        for (int i = 0; i < 16; ++i) {
            const float* src = x + (wave * 16 + nn) * IN_ + kph + i * 32 + q * 8;
            float4 f0 = *(const float4*)src;
            float4 f1 = *(const float4*)(src + 4);
            __hip_bfloat162 h0 = __float22bfloat162_rn(make_float2(f0.x, f0.y));
            __hip_bfloat162 h1 = __float22bfloat162_rn(make_float2(f0.z, f0.w));
            __hip_bfloat162 h2 = __float22bfloat162_rn(make_float2(f1.x, f1.y));
            __hip_bfloat162 h3 = __float22bfloat162_rn(make_float2(f1.z, f1.w));
            uint4 o;
            o.x = *(unsigned*)&h0; o.y = *(unsigned*)&h1;
            o.z = *(unsigned*)&h2; o.w = *(unsigned*)&h3;
            int val = i * 32 + q * 8;
            int sb  = val >> 8;
            int qp  = (val >> 6) & 3;
            int b   = (val >> 3) & 7;
            int sg  = sb * 32 + b * 4 + wave;
            int l   = qp * 16 + nn;
            x_lds[sg * 64 + l] = o;
        }
    };
    stage(kbase);   // phase 0 (x loads overlap the weight loads above)

    // ---- widened-int32 fallback: gather bytes via perm ----
    if (!u8mode) {
        const int* wpi = (const int*)wp;
#pragma unroll
        for (int ph = 0; ph < 2; ++ph)
#pragma unroll
            for (int sb = 0; sb < 2; ++sb)
#pragma unroll
                for (int cg = 0; cg < CGS; ++cg) {
                    int n = colbase + cg * 16 + nn;
                    const int* p = wpi + n * PB_ + wb + ph * 128 + sb * 64;
                    uint4 a  = *(const uint4*)p;
                    uint4 b2 = *(const uint4*)(p + 4);
                    uint4 c  = *(const uint4*)(p + 8);
                    uint4 d  = *(const uint4*)(p + 12);
                    w16[ph][sb][cg].x = __builtin_amdgcn_perm(a.y,  a.x,  0x0C0C0400) |
                                        __builtin_amdgcn_perm(a.w,  a.z,  0x04000C0C);
                    w16[ph][sb][cg].y = __builtin_amdgcn_perm(b2.y, b2.x, 0x0C0C0400) |
                                        __builtin_amdgcn_perm(b2.w, b2.z, 0x04000C0C);
                    w16[ph][sb][cg].z = __builtin_amdgcn_perm(c.y,  c.x,  0x0C0C0400) |
                                        __builtin_amdgcn_perm(c.w,  c.z,  0x04000C0C);
                    w16[ph][sb][cg].w = __builtin_amdgcn_perm(d.y,  d.x,  0x0C0C0400) |
                                        __builtin_amdgcn_perm(d.w,  d.z,  0x04000C0C);
                }
    }

    // ---- per (ph,sb,cg) scale / zero-point (1.001953125 folds RNE into trunc)
    // zps gather lives behind a REAL branch: the old ?:-select forced an
    // unconditional ~8 MB speculative gather of the 4 MB zps array.
    float sf[2][2][CGS], fb[2][2][CGS];
#pragma unroll
    for (int ph = 0; ph < 2; ++ph)
#pragma unroll
        for (int sb = 0; sb < 2; ++sb)
#pragma unroll
            for (int cg = 0; cg < CGS; ++cg) {
                int n = colbase + cg * 16 + nn;
                int g = kidx * 16 + ph * 8 + sb * 4 + q;
                sf[ph][sb][cg] = scales[n * NG_ + g] * 1.001953125f;
            }
    if (zgen) {
#pragma unroll
        for (int ph = 0; ph < 2; ++ph)
#pragma unroll
            for (int sb = 0; sb < 2; ++sb)
#pragma unroll
                for (int cg = 0; cg < CGS; ++cg) {
                    int n = colbase + cg * 16 + nn;
                    int g = kidx * 16 + ph * 8 + sb * 4 + q;
                    fb[ph][sb][cg] = -(float)zps[n * NG_ + g] * sf[ph][sb][cg];
                }
    } else {
#pragma unroll
        for (int ph = 0; ph < 2; ++ph)
#pragma unroll
            for (int sb = 0; sb < 2; ++sb)
#pragma unroll
                for (int cg = 0; cg < CGS; ++cg)
                    fb[ph][sb][cg] = -2.0f * sf[ph][sb][cg];
    }

    f32x4 acc[CGS][4];
#pragma unroll
    for (int cg = 0; cg < CGS; ++cg)
#pragma unroll
        for (int mt = 0; mt < 4; ++mt)
            acc[cg][mt] = (f32x4){0.f, 0.f, 0.f, 0.f};

    __syncthreads();   // phase-0 staging complete

    // ---- two phases x 2 superblocks x 8 ksteps ----
#pragma unroll
    for (int ph = 0; ph < 2; ++ph) {
        if (ph) {
            __syncthreads();           // everyone done reading phase-0 LDS
            stage(kbase + 512);        // phase 1
            __syncthreads();
        }
#pragma unroll
        for (int sb = 0; sb < 2; ++sb) {
#pragma unroll
            for (int d = 0; d < 4; ++d) {      // dword of the uint4
#pragma unroll
                for (int h = 0; h < 2; ++h) {
                    const int b = d * 2 + h;   // kstep 0..7
                    union { uint4 u4; s16x8 s8; } av[4];
#pragma unroll
                    for (int mt = 0; mt < 4; ++mt)
                        av[mt].u4 = x_lds[(sb * 32 + b * 4 + mt) * 64 + lane];
#pragma unroll
                    for (int cg = 0; cg < CGS; ++cg) {
                        const uint4 W = w16[ph][sb][cg];
                        const unsigned v = (d == 0) ? W.x : (d == 1) ? W.y
                                         : (d == 2) ? W.z : W.w;
                        const float s = sf[ph][sb][cg], fbv = fb[ph][sb][cg];
                        union { unsigned u[4]; s16x8 s8; } bf;
#pragma unroll
                        for (int m = 0; m < 4; ++m) {
                            const int sh = h * 16 + m * 4;
                            FU f0, f1;
                            f0.f = fmaf((float)((v >> sh) & 3u), s, fbv);
                            f1.f = fmaf((float)((v >> (sh + 2)) & 3u), s, fbv);
                            bf.u[m] = __builtin_amdgcn_perm(f1.u, f0.u, 0x07060302);
                        }
#pragma unroll
                        for (int mt = 0; mt < 4; ++mt)
                            acc[cg][mt] = __builtin_amdgcn_mfma_f32_16x16x32_bf16(
                                av[mt].s8, bf.s8, acc[cg][mt], 0, 0, 0);
                    }
                }
            }
        }
    }

    // ---- epilogue: transpose through LDS ----
    // C/D layout: col = lane&15, row = (lane>>4)*4 + reg. This wave's cols
    // within the 128-col stripe are wave*32 + cg*16 + nn.
    __syncthreads();                       // done reading x_lds as matrix A
    float* lf = (float*)x_lds;             // 64 rows x 128 cols fp32 = 32 KB
#pragma unroll
    for (int cg = 0; cg < CGS; ++cg)
#pragma unroll
        for (int mt = 0; mt < 4; ++mt)
#pragma unroll
            for (int r = 0; r < 4; ++r)
                lf[(mt * 16 + q * 4 + r) * 128 + wave * 32 + cg * 16 + nn] =
                    acc[cg][mt][r];
    __syncthreads();

    unsigned long long* flags =
        (unsigned long long*)(part + KSPLIT * (B_ * OUT_));
    const float4* ls = (const float4*)x_lds;

    if (kidx != KSPLIT - 1) {
        // ---- worker: store stripe to private plane, publish signature ----
        float* pp = part + kidx * (B_ * OUT_);
#pragma unroll
        for (int u = 0; u < 8; ++u) {
            int idx = u * 256 + tid;           // float4 index in [0, 2048)
            int row = idx >> 5;                // 0..63
            int cq  = idx & 31;                // col-quad within 128-col stripe
            *(float4*)(pp + row * OUT_ + nblk * 128 + cq * 4) = ls[idx];
        }
        __threadfence();                       // device-scope release
        __syncthreads();
        if (tid == 0)
            atomicExch(&flags[bid], sig(bid)); // device-scope publish
    } else {
        // ---- reducer: own tile is in LDS; wait for 7 siblings, reduce ----
        if (tid < KSPLIT - 1) {
            int sib = nblk * KSPLIT + tid;
            unsigned long long m = sig(sib);
            while (atomicAdd(&flags[sib], 0ull) != m)
                __builtin_amdgcn_s_sleep(1);
        }
        __syncthreads();
        __threadfence();                       // acquire side
#pragma unroll
        for (int u = 0; u < 8; ++u) {
            int idx = u * 256 + tid;
            int row = idx >> 5;
            int cq  = idx & 31;
            int off = row * OUT_ + nblk * 128 + cq * 4;
            float4 s = *(const float4*)(bias + nblk * 128 + cq * 4);
            float4 v = ls[idx];
            s.x += v.x; s.y += v.y; s.z += v.z; s.w += v.w;
#pragma unroll
            for (int p = 0; p < KSPLIT - 1; ++p) {
                float4 w = *(const float4*)(part + p * (B_ * OUT_) + off);
                s.x += w.x; s.y += w.y; s.z += w.z; s.w += w.w;
            }
            *(float4*)(out + off) = s;
        }
    }
}

extern "C" void kernel_launch(void* const* d_in, const int* in_sizes, int n_in,
                              void* d_out, int out_size, void* d_ws, size_t ws_size,
                              hipStream_t stream) {
    const float*         x      = (const float*)d_in[0];
    const unsigned char* wp     = (const unsigned char*)d_in[1];
    const float*         scales = (const float*)d_in[2];
    const int*           zps    = (const int*)d_in[3];
    const float*         bias   = (const float*)d_in[4];
    float*               out    = (float*)d_out;

    float* part = (float*)d_ws;  // 8 x 2 MB partial planes, then 4 KB flags

    k_main<<<512, 256, 0, stream>>>(x, wp, scales, zps, bias, out, part);
}

// Round 7
// 137.042 us; speedup vs baseline: 1.5358x; 1.5358x over previous
//
#include <hip/hip_runtime.h>
#include <hip/hip_bf16.h>

// out[64,8192] = x[64,8192] @ dequant(w2bit)[8192,8192]^T + bias
#define B_    64
#define IN_   8192
#define OUT_  8192
#define NG_   128      // groups per row (IN/64)
#define PB_   2048     // packed bytes per weight row (IN/4)

#define KSPLIT 16
#define KC     512     // k per block: two 256-k phases (1 superblock each)
#define CGS    2       // col-groups (16 cols) per wave -> 32 cols/wave, 128/block

typedef float f32x4 __attribute__((ext_vector_type(4)));
typedef short s16x8 __attribute__((ext_vector_type(8)));
union FU { float f; unsigned u; };

// Grid = 64 col-blocks(128 cols) x 16 k-splits = 1024 blocks = 4/CU resident
// (32 KB LDS, launch_bounds(256,4)) -> 16 waves/CU. R1 measured the 2->4
// blocks/CU step as the only lever that moved k_main; R5/R6 lost it (64 KB
// LDS). Each k-split writes a private partial plane (no atomics, no fusion —
// R6's device-scope flag polling collapsed memory BW 3x).
//
// K permuted inside 256-k SUPERBLOCKS (same permutation on x and w, dot
// products unchanged): MFMA kstep b (0..7), lane q, elem j <-> k =
// S256 + q*64 + b*8 + j. A lane's weights for one phase = 16 contiguous B;
// per block each weight row is read as 128 contiguous B (one full cache
// line). A lane's 64-k range = exactly one quant group: g = S256/64 + q.
__global__ __launch_bounds__(256, 4) void k_main(
    const float* __restrict__ x,
    const unsigned char* __restrict__ wp,
    const float* __restrict__ scales,
    const int* __restrict__ zps,
    float* __restrict__ part)
{
    __shared__ uint4 x_lds[2048];   // 32 KB: one 256-k phase, frag-slot order

    const int tid  = threadIdx.x;
    const int wave = tid >> 6;
    const int lane = tid & 63;
    const int q    = lane >> 4;
    const int nn   = lane & 15;

    const int bid     = blockIdx.x;
    const int kidx    = bid & (KSPLIT - 1);
    const int nblk    = bid >> 4;
    const int kbase   = kidx * KC;
    const int colbase = nblk * 128 + wave * 32;

    // ---- dtype-mode detection: wave-uniform scalar loads ----
    const unsigned d0 = ((const unsigned*)wp)[0];
    const unsigned d1 = ((const unsigned*)wp)[1];
    const bool u8mode = (d0 | d1) > 255u;
    const bool zgen   = (zps[0] != 2) || (zps[OUT_ * NG_ - 1] != 2);

    // ---- weight loads first: speculative packed-u8 path (real runtime
    // format), 4 x 16 B per lane covers both phases, row-contiguous.
    uint4 w16[2][CGS];
    const int wb = kidx * 128 + q * 16;     // (kbase>>2) + q*16
#pragma unroll
    for (int ph = 0; ph < 2; ++ph)
#pragma unroll
        for (int cg = 0; cg < CGS; ++cg) {
            int n = colbase + cg * 16 + nn;
            w16[ph][cg] = *(const uint4*)(wp + n * PB_ + wb + ph * 64);
        }

    // ---- scales next (they gate the first dequant): g = kidx*8 + ph*4 + q
    float sf[2][CGS], fb[2][CGS];
#pragma unroll
    for (int ph = 0; ph < 2; ++ph)
#pragma unroll
        for (int cg = 0; cg < CGS; ++cg) {
            int n = colbase + cg * 16 + nn;
            sf[ph][cg] = scales[n * NG_ + (kidx * 8 + ph * 4 + q)] * 1.001953125f;
        }
    // zps gather behind a REAL branch (a ?:-select forced an unconditional
    // ~7 MB speculative gather of the 4 MB zps array — measured R5->R6).
    if (zgen) {
#pragma unroll
        for (int ph = 0; ph < 2; ++ph)
#pragma unroll
            for (int cg = 0; cg < CGS; ++cg) {
                int n = colbase + cg * 16 + nn;
                fb[ph][cg] = -(float)zps[n * NG_ + (kidx * 8 + ph * 4 + q)]
                             * sf[ph][cg];
            }
    } else {
#pragma unroll
        for (int ph = 0; ph < 2; ++ph)
#pragma unroll
            for (int cg = 0; cg < CGS; ++cg)
                fb[ph][cg] = -2.0f * sf[ph][cg];
    }

    // ---- stage one 256-k phase: load fp32, convert, ds_write_b128 ----
    // slot (sg = b*4 + mt, l = q'*16 + nn') holds
    // x[mt*16+nn'][kph + q'*64 + b*8 .. +8) as 8 bf16.
    // thread (wave,q,nn) iter i in 0..7: val = i*32 + q*8 -> q' = val>>6,
    // b = (val>>3)&7; mt = wave; row = wave*16+nn. 16 rows x 128 B per
    // wave-iteration (full cache lines).
    auto stage = [&](int kph) {
#pragma unroll
        for (int i = 0; i < 8; ++i) {
            const float* src = x + (wave * 16 + nn) * IN_ + kph + i * 32 + q * 8;
            float4 f0 = *(const float4*)src;
            float4 f1 = *(const float4*)(src + 4);
            __hip_bfloat162 h0 = __float22bfloat162_rn(make_float2(f0.x, f0.y));
            __hip_bfloat162 h1 = __float22bfloat162_rn(make_float2(f0.z, f0.w));
            __hip_bfloat162 h2 = __float22bfloat162_rn(make_float2(f1.x, f1.y));
            __hip_bfloat162 h3 = __float22bfloat162_rn(make_float2(f1.z, f1.w));
            uint4 o;
            o.x = *(unsigned*)&h0; o.y = *(unsigned*)&h1;
            o.z = *(unsigned*)&h2; o.w = *(unsigned*)&h3;
            int val = i * 32 + q * 8;
            int qp  = val >> 6;
            int b   = (val >> 3) & 7;
            int sg  = b * 4 + wave;
            int l   = qp * 16 + nn;
            x_lds[sg * 64 + l] = o;
        }
    };
    stage(kbase);   // phase 0 (x loads queue behind the weight/scale loads)

    // ---- widened-int32 fallback: gather bytes via perm ----
    if (!u8mode) {
        const int* wpi = (const int*)wp;
#pragma unroll
        for (int ph = 0; ph < 2; ++ph)
#pragma unroll
            for (int cg = 0; cg < CGS; ++cg) {
                int n = colbase + cg * 16 + nn;
                const int* p = wpi + n * PB_ + wb + ph * 64;
                uint4 a  = *(const uint4*)p;
                uint4 b2 = *(const uint4*)(p + 4);
                uint4 c  = *(const uint4*)(p + 8);
                uint4 d  = *(const uint4*)(p + 12);
                w16[ph][cg].x = __builtin_amdgcn_perm(a.y,  a.x,  0x0C0C0400) |
                                __builtin_amdgcn_perm(a.w,  a.z,  0x04000C0C);
                w16[ph][cg].y = __builtin_amdgcn_perm(b2.y, b2.x, 0x0C0C0400) |
                                __builtin_amdgcn_perm(b2.w, b2.z, 0x04000C0C);
                w16[ph][cg].z = __builtin_amdgcn_perm(c.y,  c.x,  0x0C0C0400) |
                                __builtin_amdgcn_perm(c.w,  c.z,  0x04000C0C);
                w16[ph][cg].w = __builtin_amdgcn_perm(d.y,  d.x,  0x0C0C0400) |
                                __builtin_amdgcn_perm(d.w,  d.z,  0x04000C0C);
            }
    }

    f32x4 acc[CGS][4];
#pragma unroll
    for (int cg = 0; cg < CGS; ++cg)
#pragma unroll
        for (int mt = 0; mt < 4; ++mt)
            acc[cg][mt] = (f32x4){0.f, 0.f, 0.f, 0.f};

    __syncthreads();   // phase-0 staging complete

    // ---- two phases x 8 ksteps ----
#pragma unroll
    for (int ph = 0; ph < 2; ++ph) {
        if (ph) {
            __syncthreads();           // everyone done reading phase-0 LDS
            stage(kbase + 256);        // phase 1
            __syncthreads();
        }
#pragma unroll
        for (int d = 0; d < 4; ++d) {          // dword of the uint4
#pragma unroll
            for (int h = 0; h < 2; ++h) {
                const int b = d * 2 + h;       // kstep 0..7
                union { uint4 u4; s16x8 s8; } av[4];
#pragma unroll
                for (int mt = 0; mt < 4; ++mt)
                    av[mt].u4 = x_lds[(b * 4 + mt) * 64 + lane];
#pragma unroll
                for (int cg = 0; cg < CGS; ++cg) {
                    const uint4 W = w16[ph][cg];
                    const unsigned v = (d == 0) ? W.x : (d == 1) ? W.y
                                     : (d == 2) ? W.z : W.w;
                    const float s = sf[ph][cg], fbv = fb[ph][cg];
                    union { unsigned u[4]; s16x8 s8; } bf;
#pragma unroll
                    for (int m = 0; m < 4; ++m) {
                        const int sh = h * 16 + m * 4;
                        FU f0, f1;
                        f0.f = fmaf((float)((v >> sh) & 3u), s, fbv);
                        f1.f = fmaf((float)((v >> (sh + 2)) & 3u), s, fbv);
                        bf.u[m] = __builtin_amdgcn_perm(f1.u, f0.u, 0x07060302);
                    }
#pragma unroll
                    for (int mt = 0; mt < 4; ++mt)
                        acc[cg][mt] = __builtin_amdgcn_mfma_f32_16x16x32_bf16(
                            av[mt].s8, bf.s8, acc[cg][mt], 0, 0, 0);
                }
            }
        }
    }

    // ---- epilogue: transpose through LDS, store full-line float4 runs ----
    // C/D layout: col = lane&15, row = (lane>>4)*4 + reg. This wave's cols
    // within the 128-col stripe are wave*32 + cg*16 + nn.
    __syncthreads();                       // done reading x_lds as matrix A
    float* lf = (float*)x_lds;             // 64 rows x 128 cols fp32 = 32 KB
#pragma unroll
    for (int cg = 0; cg < CGS; ++cg)
#pragma unroll
        for (int mt = 0; mt < 4; ++mt)
#pragma unroll
            for (int r = 0; r < 4; ++r)
                lf[(mt * 16 + q * 4 + r) * 128 + wave * 32 + cg * 16 + nn] =
                    acc[cg][mt][r];
    __syncthreads();
    float* pp = part + kidx * (B_ * OUT_);
    const float4* ls = (const float4*)x_lds;
#pragma unroll
    for (int u = 0; u < 8; ++u) {
        int idx = u * 256 + tid;           // float4 index in [0, 2048)
        int row = idx >> 5;                // 0..63
        int cq  = idx & 31;                // col-quad within 128-col stripe
        *(float4*)(pp + row * OUT_ + nblk * 128 + cq * 4) = ls[idx];
    }
}

// out = bias + sum of 16 partial planes (streaming)
__global__ __launch_bounds__(256) void k_reduce(const float* __restrict__ part,
                                                const float* __restrict__ bias,
                                                float* __restrict__ out) {
    int i = (blockIdx.x * 256 + threadIdx.x) * 4;
    float4 s = *(const float4*)(bias + (i & (OUT_ - 1)));
#pragma unroll
    for (int p = 0; p < KSPLIT; ++p) {
        float4 v = *(const float4*)(part + p * (B_ * OUT_) + i);
        s.x += v.x; s.y += v.y; s.z += v.z; s.w += v.w;
    }
    *(float4*)(out + i) = s;
}

extern "C" void kernel_launch(void* const* d_in, const int* in_sizes, int n_in,
                              void* d_out, int out_size, void* d_ws, size_t ws_size,
                              hipStream_t stream) {
    const float*         x      = (const float*)d_in[0];
    const unsigned char* wp     = (const unsigned char*)d_in[1];
    const float*         scales = (const float*)d_in[2];
    const int*           zps    = (const int*)d_in[3];
    const float*         bias   = (const float*)d_in[4];
    float*               out    = (float*)d_out;

    float* part = (float*)d_ws;            // 16 x 2 MB partial planes

    k_main<<<1024, 256, 0, stream>>>(x, wp, scales, zps, part);
    k_reduce<<<512, 256, 0, stream>>>(part, bias, out);
}

// Round 8
// 131.427 us; speedup vs baseline: 1.6015x; 1.0427x over previous
//
#include <hip/hip_runtime.h>
#include <hip/hip_bf16.h>

// out[64,8192] = x[64,8192] @ dequant(w2bit)[8192,8192]^T + bias
#define B_    64
#define IN_   8192
#define OUT_  8192
#define NG_   128      // groups per row (IN/64)
#define PB_   2048     // packed bytes per weight row (IN/4)

#define KSPLIT 16
#define KC     512     // k per block: two 256-k phases (1 superblock each)
#define CGS    4       // col-groups (16 cols) per wave -> 64 cols/wave, 256/block

typedef float f32x4 __attribute__((ext_vector_type(4)));
typedef short s16x8 __attribute__((ext_vector_type(8)));
union FU { float f; unsigned u; };

// x fp32 -> bf16 (restores R0's k_pre): halves every re-read of x and turns
// k_main's staging into pure 16 B global_load_lds DMA.
__global__ __launch_bounds__(256) void k_pre(const float* __restrict__ x,
                                             __hip_bfloat16* __restrict__ xb) {
    int i = (blockIdx.x * 256 + threadIdx.x) * 4;
    float4 f = *(const float4*)(x + i);
    __hip_bfloat162 h0 = __float22bfloat162_rn(make_float2(f.x, f.y));
    __hip_bfloat162 h1 = __float22bfloat162_rn(make_float2(f.z, f.w));
    uint2 o; o.x = *(unsigned*)&h0; o.y = *(unsigned*)&h1;
    *(uint2*)(xb + i) = o;
}

// Grid = 32 col-blocks(256 cols) x 16 k-splits = 512 blocks. Block = 256 thr
// = 4 waves x 64 cols (CGS=4). REQUEST-VOLUME design: across R0-R7 every
// structural variant (occupancy 8->26%, DRAM-pattern fix, L3 warming, MLP)
// left k_main at ~44 us; the invariant was total request volume (~185 MB,
// dominated by 64x re-read of x at fp32). 256-col tiles + bf16 x cut x
// traffic 128->32 MB and total volume to ~90 MB.
//
// K permuted inside 256-k SUPERBLOCKS (same permutation on x and w):
// MFMA kstep b (0..7), lane q, elem j <-> k = S256 + q*64 + b*8 + j.
// Lane's 64-k range = one quant group: g = kidx*8 + ph*4 + q.
// Col ownership (any bijection works if weights/scales/epilogue agree):
//   n(cg) = nblk*256 + (cg>>1)*128 + wave*32 + (cg&1)*16 + nn
// so each epilogue half (cg>>1) covers a CONTIGUOUS 128-col stripe.
__global__ __launch_bounds__(256, 2) void k_main(
    const __hip_bfloat16* __restrict__ xb,
    const unsigned char* __restrict__ wp,
    const float* __restrict__ scales,
    const int* __restrict__ zps,
    float* __restrict__ part)
{
    __shared__ uint4 x_lds[2048];   // 32 KB: one 256-k phase, frag-slot order

    const int tid  = threadIdx.x;
    const int wave = tid >> 6;
    const int lane = tid & 63;
    const int q    = lane >> 4;
    const int nn   = lane & 15;

    const int bid   = blockIdx.x;
    const int kidx  = bid & (KSPLIT - 1);
    const int nblk  = bid >> 4;
    const int kbase = kidx * KC;

    int ncol[CGS];
#pragma unroll
    for (int cg = 0; cg < CGS; ++cg)
        ncol[cg] = nblk * 256 + (cg >> 1) * 128 + wave * 32 + (cg & 1) * 16 + nn;

    // ---- dtype-mode detection: wave-uniform scalar loads ----
    const unsigned d0 = ((const unsigned*)wp)[0];
    const unsigned d1 = ((const unsigned*)wp)[1];
    const bool u8mode = (d0 | d1) > 255u;
    const bool zgen   = (zps[0] != 2) || (zps[OUT_ * NG_ - 1] != 2);

    // ---- weight loads first: speculative packed-u8 path (real runtime
    // format); 8 x 16 B per lane, row-contiguous (128 B per row per block).
    uint4 w16[2][CGS];
    const int wb = kidx * 128 + q * 16;
#pragma unroll
    for (int ph = 0; ph < 2; ++ph)
#pragma unroll
        for (int cg = 0; cg < CGS; ++cg)
            w16[ph][cg] = *(const uint4*)(wp + ncol[cg] * PB_ + wb + ph * 64);

    // ---- scales (gate the first dequant): g = kidx*8 + ph*4 + q ----
    float sf[2][CGS], fb[2][CGS];
#pragma unroll
    for (int ph = 0; ph < 2; ++ph)
#pragma unroll
        for (int cg = 0; cg < CGS; ++cg)
            sf[ph][cg] = scales[ncol[cg] * NG_ + (kidx * 8 + ph * 4 + q)]
                         * 1.001953125f;
    // zps behind a REAL branch (?:-select forced a ~7 MB speculative gather).
    if (zgen) {
#pragma unroll
        for (int ph = 0; ph < 2; ++ph)
#pragma unroll
            for (int cg = 0; cg < CGS; ++cg)
                fb[ph][cg] = -(float)zps[ncol[cg] * NG_ + (kidx * 8 + ph * 4 + q)]
                             * sf[ph][cg];
    } else {
#pragma unroll
        for (int ph = 0; ph < 2; ++ph)
#pragma unroll
            for (int cg = 0; cg < CGS; ++cg)
                fb[ph][cg] = -2.0f * sf[ph][cg];
    }

    // ---- stage one 256-k phase via 16 B/lane DMA (bf16 source) ----
    // slot group sg = b*4 + mt (32 per phase); lane l = q*16+nn supplies
    // xb[mt*16+nn][kph + q*64 + b*8 .. +8) -> x_lds byte sg*1024 + l*16.
    auto stage = [&](int kph) {
#pragma unroll
        for (int i = 0; i < 8; ++i) {
            int sg = wave * 8 + i;
            int b  = sg >> 2, mt = sg & 3;
            const __hip_bfloat16* src =
                xb + (mt * 16 + nn) * IN_ + kph + q * 64 + b * 8;
            unsigned int* dst = (unsigned int*)((char*)x_lds + sg * 1024);
            __builtin_amdgcn_global_load_lds(
                (const __attribute__((address_space(1))) unsigned int*)src,
                (__attribute__((address_space(3))) unsigned int*)dst, 16, 0, 0);
        }
    };
    stage(kbase);   // phase 0 (overlaps the weight/scale loads above)

    // ---- widened-int32 fallback: gather bytes via perm (cold path) ----
    if (!u8mode) {
        const int* wpi = (const int*)wp;
#pragma unroll
        for (int ph = 0; ph < 2; ++ph)
#pragma unroll
            for (int cg = 0; cg < CGS; ++cg) {
                const int* p = wpi + ncol[cg] * PB_ + wb + ph * 64;
                uint4 a  = *(const uint4*)p;
                uint4 b2 = *(const uint4*)(p + 4);
                uint4 c  = *(const uint4*)(p + 8);
                uint4 d  = *(const uint4*)(p + 12);
                w16[ph][cg].x = __builtin_amdgcn_perm(a.y,  a.x,  0x0C0C0400) |
                                __builtin_amdgcn_perm(a.w,  a.z,  0x04000C0C);
                w16[ph][cg].y = __builtin_amdgcn_perm(b2.y, b2.x, 0x0C0C0400) |
                                __builtin_amdgcn_perm(b2.w, b2.z, 0x04000C0C);
                w16[ph][cg].z = __builtin_amdgcn_perm(c.y,  c.x,  0x0C0C0400) |
                                __builtin_amdgcn_perm(c.w,  c.z,  0x04000C0C);
                w16[ph][cg].w = __builtin_amdgcn_perm(d.y,  d.x,  0x0C0C0400) |
                                __builtin_amdgcn_perm(d.w,  d.z,  0x04000C0C);
            }
    }

    f32x4 acc[CGS][4];
#pragma unroll
    for (int cg = 0; cg < CGS; ++cg)
#pragma unroll
        for (int mt = 0; mt < 4; ++mt)
            acc[cg][mt] = (f32x4){0.f, 0.f, 0.f, 0.f};

    __syncthreads();   // phase-0 DMA drained

    // ---- two phases x 8 ksteps x 4 col-groups ----
#pragma unroll
    for (int ph = 0; ph < 2; ++ph) {
        if (ph) {
            __syncthreads();           // everyone done reading phase-0 LDS
            stage(kbase + 256);        // phase 1
            __syncthreads();           // DMA drained
        }
#pragma unroll
        for (int d = 0; d < 4; ++d) {          // dword of the uint4
#pragma unroll
            for (int h = 0; h < 2; ++h) {
                const int b = d * 2 + h;       // kstep 0..7
                union { uint4 u4; s16x8 s8; } av[4];
#pragma unroll
                for (int mt = 0; mt < 4; ++mt)
                    av[mt].u4 = x_lds[(b * 4 + mt) * 64 + lane];
#pragma unroll
                for (int cg = 0; cg < CGS; ++cg) {
                    const uint4 W = w16[ph][cg];
                    const unsigned v = (d == 0) ? W.x : (d == 1) ? W.y
                                     : (d == 2) ? W.z : W.w;
                    const float s = sf[ph][cg], fbv = fb[ph][cg];
                    union { unsigned u[4]; s16x8 s8; } bf;
#pragma unroll
                    for (int m = 0; m < 4; ++m) {
                        const int sh = h * 16 + m * 4;
                        FU f0, f1;
                        f0.f = fmaf((float)((v >> sh) & 3u), s, fbv);
                        f1.f = fmaf((float)((v >> (sh + 2)) & 3u), s, fbv);
                        bf.u[m] = __builtin_amdgcn_perm(f1.u, f0.u, 0x07060302);
                    }
#pragma unroll
                    for (int mt = 0; mt < 4; ++mt)
                        acc[cg][mt] = __builtin_amdgcn_mfma_f32_16x16x32_bf16(
                            av[mt].s8, bf.s8, acc[cg][mt], 0, 0, 0);
                }
            }
        }
    }

    // ---- epilogue: transpose through LDS in TWO 128-col halves ----
    // C/D layout: col = lane&15, row = (lane>>4)*4 + reg. Within half hh,
    // this wave's cols are wave*32 + (cg&1)*16 + nn  (cg = 2*hh + (cg&1)).
    float* pp = part + kidx * (B_ * OUT_);
    float* lf = (float*)x_lds;             // 64 rows x 128 cols fp32 = 32 KB
#pragma unroll
    for (int hh = 0; hh < 2; ++hh) {
        __syncthreads();                   // lf free (compute or prior flush)
#pragma unroll
        for (int c = 0; c < 2; ++c) {
            const int cg = hh * 2 + c;
#pragma unroll
            for (int mt = 0; mt < 4; ++mt)
#pragma unroll
                for (int r = 0; r < 4; ++r)
                    lf[(mt * 16 + q * 4 + r) * 128 + wave * 32 + c * 16 + nn] =
                        acc[cg][mt][r];
        }
        __syncthreads();
#pragma unroll
        for (int u = 0; u < 8; ++u) {
            int idx = u * 256 + tid;       // float4 index in [0, 2048)
            int row = idx >> 5;            // 0..63
            int cq  = idx & 31;            // col-quad within 128-col half
            *(float4*)(pp + row * OUT_ + nblk * 256 + hh * 128 + cq * 4) =
                ((const float4*)x_lds)[idx];
        }
    }
}

// out = bias + sum of 16 partial planes (streaming)
__global__ __launch_bounds__(256) void k_reduce(const float* __restrict__ part,
                                                const float* __restrict__ bias,
                                                float* __restrict__ out) {
    int i = (blockIdx.x * 256 + threadIdx.x) * 4;
    float4 s = *(const float4*)(bias + (i & (OUT_ - 1)));
#pragma unroll
    for (int p = 0; p < KSPLIT; ++p) {
        float4 v = *(const float4*)(part + p * (B_ * OUT_) + i);
        s.x += v.x; s.y += v.y; s.z += v.z; s.w += v.w;
    }
    *(float4*)(out + i) = s;
}

extern "C" void kernel_launch(void* const* d_in, const int* in_sizes, int n_in,
                              void* d_out, int out_size, void* d_ws, size_t ws_size,
                              hipStream_t stream) {
    const float*         x      = (const float*)d_in[0];
    const unsigned char* wp     = (const unsigned char*)d_in[1];
    const float*         scales = (const float*)d_in[2];
    const int*           zps    = (const int*)d_in[3];
    const float*         bias   = (const float*)d_in[4];
    float*               out    = (float*)d_out;

    __hip_bfloat16* xb   = (__hip_bfloat16*)d_ws;             // 1 MB
    float*          part = (float*)((char*)d_ws + (1 << 20)); // 16 x 2 MB

    k_pre<<<512, 256, 0, stream>>>(x, xb);
    k_main<<<512, 256, 0, stream>>>(xb, wp, scales, zps, part);
    k_reduce<<<512, 256, 0, stream>>>(part, bias, out);
}